// Round 12
// baseline (378.549 us; speedup 1.0000x reference)
//
#include <hip/hip_runtime.h>
#include <hip/hip_bf16.h>

#define NNODES 100000
#define HALFN 50000       // counts are u16-packed: 2 nodes per u32
#define NEDGES 1600000
#define KDIM 256
#define ODIM 128
#define NXCD 8            // counts/bases replicated per-XCD; selected by HW_REG_XCC_ID
#define NB_SCAN 391       // ceil(100000 / 256)
#define EDGE_CAP 1900032  // total (<=1.9M) + slack >= 8 for spmm prefetch overread
#define GEMM_BLOCKS 1563  // ceil(100000 / 64)
#define EDGE_BLOCKS 1563  // ceil(400000 / 256); thread i owns edges [4i, 4i+4)
#define CONV_BLOCKS 128   // ceil(32768 / 256)
#define ZERO_BLOCKS 1563  // 8*50000 u32 / 256

typedef __attribute__((ext_vector_type(8))) short short8;
typedef __attribute__((ext_vector_type(4))) float floatx4;

// round-to-nearest-even f32 -> bf16 (inputs are finite Gaussians; no NaN handling needed)
static __device__ __forceinline__ short f2bf(float f) {
  union { float f; unsigned u; } x; x.f = f;
  unsigned r = (x.u + 0x7fffu + ((x.u >> 16) & 1u)) >> 16;
  return (short)r;
}

// K0: init — conv_w (128 blocks) + zero the packed per-XCD counts (1.6 MB).
__global__ __launch_bounds__(256) void init_kernel(
    const float* __restrict__ W, short* __restrict__ Wb,
    unsigned* __restrict__ counts) {
  if (blockIdx.x < CONV_BLOCKS) {
    int i = blockIdx.x * 256 + threadIdx.x;
    if (i < ODIM * KDIM) Wb[i] = f2bf(W[i]);
    return;
  }
  int i = (blockIdx.x - CONV_BLOCKS) * 256 + threadIdx.x;
  if (i < NXCD * HALFN) counts[i] = 0u;
}

// K1: gemm (blocks [0, GEMM_BLOCKS)) || rank (blocks after).
//
// rank: counts are PACKED — two nodes per u32 (node n -> word n>>1, halfword
// n&1; per-XCD degree < 256 so no carry into the neighbor half). Per-XCD copy
// is 200 KB (was 400): smaller hot footprint survives L2 under gemm's 102 MB
// X stream -> fewer L2-miss RMWs (the ~46 MB excess WRITE_SIZE).
// rank stores (xcc<<8)|local_rank.
//
// gemm: r10 reg version (no LDS -> rank blocks keep full occupancy): 64
// rows/block, 16 rows/wave, all 8 n-tiles/wave; K-loop fully unrolled, 2-deep
// register double-buffer on the X loads.
// D layout: col = t*16 + (lane&15), row = quad*4 + reg  [m89 layout]
// H stored PACKED: u32 word j = (bf16 col j) | (bf16 col j+64)<<16.
__global__ __launch_bounds__(256) void gemm_rank_kernel(
    const float* __restrict__ X, const short* __restrict__ Wb,
    const float* __restrict__ bias, unsigned* __restrict__ H2,
    const int* __restrict__ rows, unsigned* __restrict__ counts,
    unsigned short* __restrict__ rank) {
  if (blockIdx.x >= GEMM_BLOCKS) {
    // ---- rank path: exact partition, thread owns edges [4i, 4i+4) ----
    unsigned xcc;
    asm("s_getreg_b32 %0, hwreg(HW_REG_XCC_ID)" : "=s"(xcc));
    xcc &= 7u;
    unsigned* cbase = counts + (size_t)xcc * HALFN;
    const int e0 = ((blockIdx.x - GEMM_BLOCKS) * 256 + threadIdx.x) * 4;
    if (e0 < NEDGES) {
      const int4 r4 = *(const int4*)(rows + e0);
      const unsigned s0 = (r4.x & 1) << 4, s1 = (r4.y & 1) << 4;
      const unsigned s2 = (r4.z & 1) << 4, s3 = (r4.w & 1) << 4;
      const unsigned o0 = (__hip_atomic_fetch_add(&cbase[r4.x >> 1], 1u << s0,
                            __ATOMIC_RELAXED, __HIP_MEMORY_SCOPE_WORKGROUP) >> s0) & 0xffffu;
      const unsigned o1 = (__hip_atomic_fetch_add(&cbase[r4.y >> 1], 1u << s1,
                            __ATOMIC_RELAXED, __HIP_MEMORY_SCOPE_WORKGROUP) >> s1) & 0xffffu;
      const unsigned o2 = (__hip_atomic_fetch_add(&cbase[r4.z >> 1], 1u << s2,
                            __ATOMIC_RELAXED, __HIP_MEMORY_SCOPE_WORKGROUP) >> s2) & 0xffffu;
      const unsigned o3 = (__hip_atomic_fetch_add(&cbase[r4.w >> 1], 1u << s3,
                            __ATOMIC_RELAXED, __HIP_MEMORY_SCOPE_WORKGROUP) >> s3) & 0xffffu;
      ushort4 rk;
      rk.x = (unsigned short)((xcc << 8) | o0);
      rk.y = (unsigned short)((xcc << 8) | o1);
      rk.z = (unsigned short)((xcc << 8) | o2);
      rk.w = (unsigned short)((xcc << 8) | o3);
      *(ushort4*)(rank + e0) = rk;   // 8 B aligned (e0 % 4 == 0)
    }
    return;
  }
  // ---- gemm path ----
  const int lane = threadIdx.x & 63;
  const int wave = threadIdx.x >> 6;
  const int l16 = lane & 15;
  const int quad = lane >> 4;
  const int rowBase = blockIdx.x * 64 + wave * 16;
  const int arow = rowBase + l16;
  const bool inb = arow < NNODES;
  const float4 zf4 = {0.f, 0.f, 0.f, 0.f};
  const float4* xp = (const float4*)(X + (size_t)(inb ? arow : 0) * KDIM + quad * 8);

  floatx4 acc[8];
#pragma unroll
  for (int t = 0; t < 8; t++) acc[t] = (floatx4){0.f, 0.f, 0.f, 0.f};

  float4 c0 = inb ? xp[0] : zf4;
  float4 c1 = inb ? xp[1] : zf4;
#pragma unroll
  for (int k0 = 0; k0 < 8; k0++) {
    float4 n0, n1;
    if (k0 < 7) {
      n0 = inb ? xp[(k0 + 1) * 8] : zf4;
      n1 = inb ? xp[(k0 + 1) * 8 + 1] : zf4;
    }
    short8 a;
    a[0] = f2bf(c0.x); a[1] = f2bf(c0.y); a[2] = f2bf(c0.z); a[3] = f2bf(c0.w);
    a[4] = f2bf(c1.x); a[5] = f2bf(c1.y); a[6] = f2bf(c1.z); a[7] = f2bf(c1.w);
    const short* bp = Wb + k0 * 32 + quad * 8;
#pragma unroll
    for (int t = 0; t < 8; t++) {
      short8 b = *(const short8*)(bp + (size_t)(t * 16 + l16) * KDIM);
      acc[t] = __builtin_amdgcn_mfma_f32_16x16x32_bf16(a, b, acc[t], 0, 0, 0);
    }
    if (k0 < 7) { c0 = n0; c1 = n1; }
  }

#pragma unroll
  for (int t = 0; t < 4; t++) {
    const int cl = t * 16 + l16;
    const float blo = bias[cl];
    const float bhi = bias[cl + 64];
#pragma unroll
    for (int r = 0; r < 4; r++) {
      const int row = rowBase + quad * 4 + r;
      if (row < NNODES) {
        unsigned lo = (unsigned short)f2bf(acc[t][r] + blo);
        unsigned hi = (unsigned short)f2bf(acc[t + 4][r] + bhi);
        H2[(size_t)row * 64 + cl] = lo | (hi << 16);
      }
    }
  }
}

// K2: scan1. Per node sum the 8 per-XCD packed counts, pad to multiple of 4,
// block-level exclusive scan -> chunkExcl + blockSums.
__global__ __launch_bounds__(256) void scan1_kernel(
    const unsigned* __restrict__ counts, int* __restrict__ chunkExcl,
    int* __restrict__ blockSums) {
  __shared__ int s[256];
  int t = threadIdx.x;
  int n = blockIdx.x * 256 + t;
  int sum = 0;
  if (n < NNODES) {
    const unsigned sh = (n & 1) << 4;
    int s0 = 0;
#pragma unroll
    for (int x = 0; x < NXCD; x++)
      s0 += (int)((counts[(size_t)x * HALFN + (n >> 1)] >> sh) & 0xffffu);
    sum = (s0 + 3) & ~3;  // pad segment to multiple of 4 records
  }
  s[t] = sum;
  __syncthreads();
  for (int o = 1; o < 256; o <<= 1) {
    int add = (t >= o) ? s[t - o] : 0;
    __syncthreads();
    s[t] += add;
    __syncthreads();
  }
  if (n < NNODES) chunkExcl[n] = s[t] - sum;
  if (t == 255) blockSums[blockIdx.x] = s[255];
}

// K3: merged scan2+scan3+pad-write (391 blocks x 512). Each block redundantly
// scans the 391 blockSums in LDS for its base; per node writes offsets[n],
// expands the packed per-XCD counts into absolute u32 base positions in sbase
// (bases exceed 16 bits so they get their own array), zeroes the <=3 pad
// records (replaces the edges memset).
__global__ __launch_bounds__(512) void scan23_kernel(
    const int* __restrict__ blockSums, const int* __restrict__ chunkExcl,
    const unsigned* __restrict__ counts, unsigned* __restrict__ sbase,
    int* __restrict__ offsets, int2* __restrict__ edges) {
  __shared__ int s[512];
  const int t = threadIdx.x;
  s[t] = (t < NB_SCAN) ? blockSums[t] : 0;
  __syncthreads();
  for (int o = 1; o < 512; o <<= 1) {
    int add = (t >= o) ? s[t - o] : 0;
    __syncthreads();
    s[t] += add;
    __syncthreads();
  }
  const int myBase = (blockIdx.x == 0) ? 0 : s[blockIdx.x - 1];
  if (blockIdx.x == 0 && t == 0) offsets[NNODES] = s[NB_SCAN - 1];
  if (t < 256) {
    const int n = blockIdx.x * 256 + t;
    if (n < NNODES) {
      const int run = chunkExcl[n] + myBase;   // multiple of 4
      offsets[n] = run;
      const unsigned sh = (n & 1) << 4;
      int deg = 0;
      int acc2 = run;
#pragma unroll
      for (int x = 0; x < NXCD; x++) {
        const int c = (int)((counts[(size_t)x * HALFN + (n >> 1)] >> sh) & 0xffffu);
        sbase[(size_t)x * NNODES + n] = (unsigned)acc2;
        acc2 += c;
        deg += c;
      }
      const int padded = (deg + 3) & ~3;
      const int2 zrec = {0, 0};
      for (int p = run + deg; p < run + padded; p++) edges[p] = zrec;  // pad = {col 0, val 0}
    }
  }
}

// K4: atomic-free placement: pos = sbase[xcc_at_rank_time][row] + local_rank.
__global__ __launch_bounds__(256) void place_kernel(
    const int* __restrict__ rows, const int* __restrict__ cols,
    const float* __restrict__ vals, const unsigned short* __restrict__ rank,
    const unsigned* __restrict__ sbase, int2* __restrict__ edges) {
  const int e0 = (blockIdx.x * 256 + threadIdx.x) * 4;
  if (e0 < NEDGES) {
    const int4 r4 = *(const int4*)(rows + e0);
    const int4 c4 = *(const int4*)(cols + e0);
    const float4 v4 = *(const float4*)(vals + e0);
    const ushort4 k4 = *(const ushort4*)(rank + e0);
    int2 rec;
    rec.x = c4.x; rec.y = __float_as_int(v4.x);
    edges[(int)sbase[(size_t)(k4.x >> 8) * NNODES + r4.x] + (int)(k4.x & 255u)] = rec;
    rec.x = c4.y; rec.y = __float_as_int(v4.y);
    edges[(int)sbase[(size_t)(k4.y >> 8) * NNODES + r4.y] + (int)(k4.y & 255u)] = rec;
    rec.x = c4.z; rec.y = __float_as_int(v4.z);
    edges[(int)sbase[(size_t)(k4.z >> 8) * NNODES + r4.z] + (int)(k4.z & 255u)] = rec;
    rec.x = c4.w; rec.y = __float_as_int(v4.w);
    edges[(int)sbase[(size_t)(k4.w >> 8) * NNODES + r4.w] + (int)(k4.w & 255u)] = rec;
  }
}

// K5: one wave per output row; lane owns channels {lane, lane+64}. 4 edges per
// iter with NEXT-BATCH PREFETCH: batch i+1's records load while batch i's H
// gathers are in flight -> the serial (edge-load 600cy -> gather 600cy) chain
// becomes ~600cy/iter. Unconditional prefetch is in-bounds: max read index =
// total+7 and total+8 <= EDGE_CAP. Segments padded to multiple of 4 (pads are
// {col 0, val 0}) -> no tail loop.
__global__ __launch_bounds__(256) void spmm_kernel(const int* __restrict__ offsets,
                                                   const int2* __restrict__ edges,
                                                   const unsigned* __restrict__ H2,
                                                   float* __restrict__ out) {
  const int lane = threadIdx.x & 63;
  const int row = blockIdx.x * 4 + (threadIdx.x >> 6);
  if (row >= NNODES) return;
  const int s = offsets[row];      // multiple of 4
  const int e = offsets[row + 1];
  float ax = 0.f, ay = 0.f;
  if (s < e) {
    int i = s;
    int4 p01 = *(const int4*)(edges + i);      // 16 B aligned (s % 4 == 0)
    int4 p23 = *(const int4*)(edges + i + 2);
    for (;;) {
      const int inext = i + 4;
      const int4 q01 = *(const int4*)(edges + inext);      // prefetch (may be dead)
      const int4 q23 = *(const int4*)(edges + inext + 2);
      const unsigned h0 = H2[(size_t)p01.x * 64 + lane];
      const unsigned h1 = H2[(size_t)p01.z * 64 + lane];
      const unsigned h2 = H2[(size_t)p23.x * 64 + lane];
      const unsigned h3 = H2[(size_t)p23.z * 64 + lane];
      const float v0 = __int_as_float(p01.y), v1 = __int_as_float(p01.w);
      const float v2 = __int_as_float(p23.y), v3 = __int_as_float(p23.w);
      ax += v0 * __uint_as_float(h0 << 16);            // col = lane
      ay += v0 * __uint_as_float(h0 & 0xffff0000u);    // col = lane + 64
      ax += v1 * __uint_as_float(h1 << 16);
      ay += v1 * __uint_as_float(h1 & 0xffff0000u);
      ax += v2 * __uint_as_float(h2 << 16);
      ay += v2 * __uint_as_float(h2 & 0xffff0000u);
      ax += v3 * __uint_as_float(h3 << 16);
      ay += v3 * __uint_as_float(h3 & 0xffff0000u);
      if (inext >= e) break;
      p01 = q01; p23 = q23; i = inext;
    }
  }
  out[(size_t)row * 128 + lane] = ax;
  out[(size_t)row * 128 + 64 + lane] = ay;
}

extern "C" void kernel_launch(void* const* d_in, const int* in_sizes, int n_in,
                              void* d_out, int out_size, void* d_ws, size_t ws_size,
                              hipStream_t stream) {
  const float* X = (const float*)d_in[0];
  const int* erow = (const int*)d_in[1];
  const int* ecol = (const int*)d_in[2];
  const float* eval = (const float*)d_in[3];
  const float* W = (const float*)d_in[4];
  const float* bias = (const float*)d_in[5];
  float* out = (float*)d_out;

  char* ws = (char*)d_ws;
  size_t off = 0;
  auto alloc = [&](size_t bytes) -> char* {
    char* p = ws + off;
    off += (bytes + 255) & ~(size_t)255;
    return p;
  };
  unsigned* Hb = (unsigned*)alloc((size_t)NNODES * 64 * 4);       // 25.6 MB packed
  short* Wb = (short*)alloc((size_t)ODIM * KDIM * 2);             // 64 KB
  unsigned* counts = (unsigned*)alloc((size_t)NXCD * HALFN * 4);  // 1.6 MB packed u16 pairs
  unsigned* sbase = (unsigned*)alloc((size_t)NXCD * NNODES * 4);  // 3.2 MB u32 bases
  int* chunkExcl = (int*)alloc((size_t)NNODES * 4);
  int* offsets = (int*)alloc((size_t)(NNODES + 1) * 4);
  int* blockSums = (int*)alloc((size_t)NB_SCAN * 4);
  unsigned short* rank = (unsigned short*)alloc((size_t)NEDGES * 2);  // 3.2 MB
  int2* edges = (int2*)alloc((size_t)EDGE_CAP * 8);  // 15.2 MB, padded CSR records

  init_kernel<<<CONV_BLOCKS + ZERO_BLOCKS, 256, 0, stream>>>(W, Wb, counts);
  gemm_rank_kernel<<<GEMM_BLOCKS + EDGE_BLOCKS, 256, 0, stream>>>(X, Wb, bias, Hb,
                                                                  erow, counts, rank);
  scan1_kernel<<<NB_SCAN, 256, 0, stream>>>(counts, chunkExcl, blockSums);
  scan23_kernel<<<NB_SCAN, 512, 0, stream>>>(blockSums, chunkExcl, counts, sbase,
                                             offsets, edges);
  place_kernel<<<EDGE_BLOCKS, 256, 0, stream>>>(erow, ecol, eval, rank, sbase, edges);
  spmm_kernel<<<(NNODES + 3) / 4, 256, 0, stream>>>(offsets, edges, (const unsigned*)Hb, out);
}